// Round 5
// baseline (124.909 us; speedup 1.0000x reference)
//
#include <hip/hip_runtime.h>
#include <cstdint>

// BasisFunction1D: out[o,b] = sum_i (1-d)*P[idx,o,i] + d*P[idx+1,o,i]
//
// R11: latency-tolerant main_k + fused build.
//   main_k: 1024 blocks x 512 thr (32s x 2ih x 16bt), 4 blocks/CU = 4 barrier
//     domains, 32 waves/CU, VGPR budget 64 (launch_bounds(512,8)) so per-phase
//     prefetch (2xQ uint4 + 2xT uint4) stays in flight across the 8 gathers.
//   T2[b][i] transposed: per-phase T prefetch = 2 dwordx4 (was 8 dwords).
//   Bijective XCD swizzle: xcd = (s&3)|((bt&1)<<2) -> per-XCD unique Q2 2MB +
//     T2 1MB, L2-resident. reduce_k remapped to the writers' XCD.
//   part stores PLAIN (L2-resident for reduce_k; R10's NT forced HBM RMW).
//   build_q & build_t fused into one dispatch (one less launch gap).

#define NG 128
#define NI 128
#define NO 128
#define NB 8192
#define WO 4
#define PH 8

using half2v  = __attribute__((ext_vector_type(2))) _Float16;
using float4v = __attribute__((ext_vector_type(4))) float;

__device__ inline uint32_t pack_f16x2(float lo, float hi) {
    _Float16 hl = (_Float16)lo, hh = (_Float16)hi;
    return (uint32_t)__builtin_bit_cast(unsigned short, hl) |
           ((uint32_t)__builtin_bit_cast(unsigned short, hh) << 16);
}

// ---- K1 (fused): blocks 0..255 -> Q2 packer; blocks 256..383 -> T2 ----
// Q2[((s*NI+i)*NG+g)*4+ow] = pack(P[g,o,i], P[g+1,o,i]-P[g,o,i]), o=s*4+ow.
// T2[b][i] = (idx*16) | (f16(d)<<16)  (transposed from R10's T[i][b]).
__global__ __launch_bounds__(256) void build_k(const float* __restrict__ P,
                                               const float* __restrict__ x,
                                               const float* __restrict__ borders,
                                               const float* __restrict__ icl,
                                               uint32_t* __restrict__ Q2,
                                               uint32_t* __restrict__ T2) {
    __shared__ __align__(16) char smem[40960];
    const int t = threadIdx.x;
    if (blockIdx.x < 256) {
        float (*L)[16][128] = (float (*)[16][128])smem;   // [5][16][128]
        const int gb = blockIdx.x >> 3;
        const int ob = blockIdx.x & 7;
        const int g0 = gb * 4, o0 = ob * 16, s0 = ob * 4;
        #pragma unroll
        for (int pass = 0; pass < 40; ++pass) {           // 80 rows x 128 i
            int row = pass * 2 + (t >> 7);
            int i   = t & 127;
            int gg  = row >> 4, ol = row & 15;
            L[gg][ol][i] = P[(size_t)(g0 + gg) * (NO * NI) + (o0 + ol) * NI + i];
        }
        __syncthreads();
        #pragma unroll
        for (int pp = 0; pp < 2; ++pp) {
            int item = pp * 256 + t;                      // 4 sl x 128 i
            int i  = item & 127;
            int sl = item >> 7;
            uint32_t* dst = Q2 + ((size_t)((s0 + sl) * NI + i) * NG + g0) * 4;
            #pragma unroll
            for (int gg = 0; gg < 4; ++gg) {
                uint32_t r[4];
                #pragma unroll
                for (int ow = 0; ow < 4; ++ow) {
                    float pl = L[gg][sl * 4 + ow][i];
                    float dd = L[gg + 1][sl * 4 + ow][i] - pl;
                    r[ow] = pack_f16x2(pl, dd);
                }
                *(uint4*)(dst + gg * 4) = make_uint4(r[0], r[1], r[2], r[3]);
            }
        }
    } else {
        uint32_t (*Lt)[65] = (uint32_t (*)[65])smem;      // [128][65]
        const int b0 = (blockIdx.x - 256) * 64;           // 64-b x 128-i tile
        #pragma unroll
        for (int f = 0; f < 8; ++f) {
            int q  = f * 256 + t;
            int i  = q >> 4;
            int c4 = (q & 15) * 4;
            const float4 xv = *(const float4*)(x + (size_t)i * NB + b0 + c4);
            const float xs[4] = {xv.x, xv.y, xv.z, xv.w};
            #pragma unroll
            for (int j = 0; j < 4; ++j) {
                float v = xs[j];
                float ea = __expf(-fabsf(v));
                float cdf = v > 0.f ? 1.f - 0.5f * ea : 0.5f * ea;
                int idx = (int)(cdf * 128.f);
                idx = idx > 127 ? 127 : idx;
                float d = (v - borders[idx]) * icl[idx];
                _Float16 hd = (_Float16)d;
                Lt[i][c4 + j] = ((uint32_t)idx << 4) |
                                ((uint32_t)__builtin_bit_cast(unsigned short, hd) << 16);
            }
        }
        __syncthreads();
        #pragma unroll
        for (int k = 0; k < 8; ++k) {                     // 1KB/wave-instr
            int flat = t * 4 + k * 1024;                  // word in 64x128 tile
            int bl = flat >> 7;
            int i0 = flat & 127;
            uint4 r = make_uint4(Lt[i0][bl], Lt[i0 + 1][bl],
                                 Lt[i0 + 2][bl], Lt[i0 + 3][bl]);
            *(uint4*)(T2 + (size_t)(b0 + bl) * NI + i0) = r;
        }
    }
}

// ---- K2: main. 512 thr; 512 b x 4 o x 64 i; 4 blocks/CU; pipelined ----
__global__ __launch_bounds__(512, 8) void main_k(const uint32_t* __restrict__ Q2,
                                                 const uint32_t* __restrict__ T2,
                                                 float* __restrict__ part) {
    __shared__ __align__(16) uint32_t slab[2][PH][512];   // 32 KB
    const int t    = threadIdx.x;
    const int bx   = blockIdx.x;
    const int xcd  = bx & 7;
    const int rest = bx >> 3;
    const int s    = ((rest & 7) << 2) | (xcd & 3);       // o-slice (4 o)
    const int ih   = (rest >> 3) & 1;                     // i-half (64 i)
    const int bt   = (((rest >> 4) & 7) << 1) | (xcd >> 2); // b-tile (512 b)
    const int bme  = (bt << 9) | t;
    const uint32_t* Qs = Q2 + ((size_t)s * NI + ih * 64) * (NG * WO);
    const uint32_t* Tr = T2 + (size_t)bme * NI + ih * 64;

    float a0 = 0.f, a1 = 0.f, a2 = 0.f, a3 = 0.f;

    // prologue: stage phase 0 (16 KB; 2x16B per thread) + 8 T words (2x16B)
    uint4 ta = *(const uint4*)(Tr);
    uint4 tb = *(const uint4*)(Tr + 4);
    {
        uint4 qa = *(const uint4*)(Qs + (size_t)t * 4);
        uint4 qb = *(const uint4*)(Qs + 2048 + (size_t)t * 4);
        ((uint4*)&slab[0][0][0])[t]       = qa;
        ((uint4*)&slab[0][0][0])[t + 512] = qb;
    }
    __syncthreads();

    #pragma unroll
    for (int p = 0; p < 8; ++p) {
        const int cur = p & 1;
        uint4 qna, qnb, tna, tnb;
        if (p < 7) {                        // issue next-phase loads FIRST
            const uint32_t* qsrc = Qs + (size_t)(p + 1) * 4096;
            qna = *(const uint4*)(qsrc + (size_t)t * 4);
            qnb = *(const uint4*)(qsrc + 2048 + (size_t)t * 4);
            tna = *(const uint4*)(Tr + (p + 1) * 8);
            tnb = *(const uint4*)(Tr + (p + 1) * 8 + 4);
        }
        const char* sp = (const char*)&slab[cur][0][0];
        const uint32_t tc[8] = {ta.x, ta.y, ta.z, ta.w, tb.x, tb.y, tb.z, tb.w};
        #pragma unroll
        for (int il = 0; il < PH; ++il) {
            uint32_t tw  = tc[il];
            uint32_t off = tw & 0xFFFFu;                    // idx*16 bytes
            uint32_t w2b = (tw & 0xFFFF0000u) | 0x3C00u;    // {1.0h, d}
            uint4 q = *(const uint4*)(sp + il * 2048 + off);
            half2v w2 = __builtin_bit_cast(half2v, w2b);
            a0 = __builtin_amdgcn_fdot2(__builtin_bit_cast(half2v, q.x), w2, a0, false);
            a1 = __builtin_amdgcn_fdot2(__builtin_bit_cast(half2v, q.y), w2, a1, false);
            a2 = __builtin_amdgcn_fdot2(__builtin_bit_cast(half2v, q.z), w2, a2, false);
            a3 = __builtin_amdgcn_fdot2(__builtin_bit_cast(half2v, q.w), w2, a3, false);
        }
        if (p < 7) {
            ((uint4*)&slab[cur ^ 1][0][0])[t]       = qna;
            ((uint4*)&slab[cur ^ 1][0][0])[t + 512] = qnb;
            ta = tna; tb = tnb;
            __syncthreads();
        }
    }

    // partial store (PLAIN -> L2-resident for reduce_k); 2KB runs per o
    float* po = part + (size_t)ih * (NO * NB) + (size_t)(s * 4) * NB + bme;
    po[0]                = a0;
    po[NB]               = a1;
    po[2 * (size_t)NB]   = a2;
    po[3 * (size_t)NB]   = a3;
}

// ---- K3: out = part0 + part1, XCD-matched to the partial writers ----
__global__ __launch_bounds__(128) void reduce_k(const float* __restrict__ part,
                                                float* __restrict__ out) {
    const int rb   = blockIdx.x;                 // 2048 blocks
    const int xcd  = rb & 7;
    const int rest = rb >> 3;
    const int olo  = rest & 3;
    const int ohi  = (rest >> 2) & 7;
    const int bthi = (rest >> 5) & 7;
    const int o    = (ohi << 4) | ((xcd & 3) << 2) | olo;
    const int bt   = (bthi << 1) | (xcd >> 2);
    const int e0   = o * NB + bt * 512 + threadIdx.x * 4;
    const float4v v0 = *(const float4v*)(part + e0);
    const float4v v1 = *(const float4v*)(part + (size_t)NO * NB + e0);
    const float4v r  = v0 + v1;
    __builtin_nontemporal_store(r, (float4v*)(out + e0));
}

extern "C" void kernel_launch(void* const* d_in, const int* in_sizes, int n_in,
                              void* d_out, int out_size, void* d_ws, size_t ws_size,
                              hipStream_t stream) {
    const float* x       = (const float*)d_in[0];
    const float* P       = (const float*)d_in[1];
    const float* borders = (const float*)d_in[2];
    const float* icl     = (const float*)d_in[3];
    float* out = (float*)d_out;

    uint32_t* Q2  = (uint32_t*)d_ws;                 // 8 MB
    uint32_t* T2  = Q2 + (size_t)NO * NI * NG;       // 4 MB
    float*    prt = (float*)(T2 + (size_t)NI * NB);  // 8 MB (two halves)

    hipLaunchKernelGGL(build_k, dim3(384), dim3(256), 0, stream,
                       P, x, borders, icl, Q2, T2);
    hipLaunchKernelGGL(main_k, dim3(1024), dim3(512), 0, stream, Q2, T2, prt);
    hipLaunchKernelGGL(reduce_k, dim3(2048), dim3(128), 0, stream, prt, out);
}

// Round 6
// 99.974 us; speedup vs baseline: 1.2494x; 1.2494x over previous
//
#include <hip/hip_runtime.h>
#include <cstdint>

// BasisFunction1D: out[o,b] = sum_i (1-d)*P[idx,o,i] + d*P[idx+1,o,i]
//
// R12: async-staged, partial-free main_k.
//   R11 post-mortem: main_k was HBM-bound (127MB: L2 thrash + spill churn);
//   occupancy proven irrelevant (R9/R10). The real cost is per-phase serial
//   load->vmcnt->ds_write->lgkm->barrier. R12 removes it:
//   - global_load_lds width=16 staging, issued one full phase early; the
//     single vmcnt(0)+barrier per phase drains loads with ~2us of compute
//     in between (async direct-to-LDS, no VGPR round trip).
//   - block = 1024 b x 4 o x ALL 128 i -> direct out, no partials/reduce.
//   - 16-i phases (2x32KB LDS double buffer), 8 barriers total.
//   - T2[b][i]: per phase per thread one 64B line (4x dwordx4).
//   - grid 256 = 32 s x 8 bt, 1 block/CU; xcd = bx&7 groups 4 Q-slabs
//     (1MB) per XCD.

#define NG 128
#define NI 128
#define NO 128
#define NB 8192
#define PH 16
#define NPH 8

using half2v = __attribute__((ext_vector_type(2))) _Float16;

__device__ inline uint32_t pack_f16x2(float lo, float hi) {
    _Float16 hl = (_Float16)lo, hh = (_Float16)hi;
    return (uint32_t)__builtin_bit_cast(unsigned short, hl) |
           ((uint32_t)__builtin_bit_cast(unsigned short, hh) << 16);
}

__device__ inline void load_lds16(const uint32_t* g, uint32_t* l) {
    __builtin_amdgcn_global_load_lds(
        (const __attribute__((address_space(1))) uint32_t*)g,
        (__attribute__((address_space(3))) uint32_t*)l, 16, 0, 0);
}

// ---- K1: P[g,o,i] -> Q2[((s*NI+i)*NG+g)*4+ow] = pack(P, dP), o=s*4+ow ----
// (verified R10 version: 64B-contiguous stores, ~4us)
__global__ __launch_bounds__(256) void build_q(const float* __restrict__ P,
                                               uint32_t* __restrict__ Q2) {
    __shared__ float L[5][16][128];             // 40 KB
    const int gb = blockIdx.x >> 3;
    const int ob = blockIdx.x & 7;
    const int g0 = gb * 4;
    const int o0 = ob * 16;
    const int s0 = ob * 4;
    const int t  = threadIdx.x;
    #pragma unroll
    for (int pass = 0; pass < 40; ++pass) {     // 80 rows x 128 i
        int row = pass * 2 + (t >> 7);
        int i   = t & 127;
        int gg  = row >> 4, ol = row & 15;
        L[gg][ol][i] = P[(size_t)(g0 + gg) * (NO * NI) + (o0 + ol) * NI + i];
    }
    __syncthreads();
    #pragma unroll
    for (int pp = 0; pp < 2; ++pp) {
        int item = pp * 256 + t;                // 4 sl x 128 i
        int i  = item & 127;
        int sl = item >> 7;
        uint32_t* dst = Q2 + ((size_t)((s0 + sl) * NI + i) * NG + g0) * 4;
        #pragma unroll
        for (int gg = 0; gg < 4; ++gg) {
            uint32_t r[4];
            #pragma unroll
            for (int ow = 0; ow < 4; ++ow) {
                float pl = L[gg][sl * 4 + ow][i];
                float dd = L[gg + 1][sl * 4 + ow][i] - pl;
                r[ow] = pack_f16x2(pl, dd);
            }
            *(uint4*)(dst + gg * 4) = make_uint4(r[0], r[1], r[2], r[3]);
        }
    }
}

// ---- K2: bucketize x -> T2[b][i] = (idx*16) | (f16(d) << 16) -------------
// 64-b x 128-i tile per block; LDS transpose; 512B-contiguous stores.
__global__ __launch_bounds__(256) void build_t2(const float* __restrict__ x,
                                                const float* __restrict__ borders,
                                                const float* __restrict__ icl,
                                                uint32_t* __restrict__ T2) {
    __shared__ uint32_t Lt[128][65];            // 33 KB
    const int t  = threadIdx.x;
    const int b0 = blockIdx.x * 64;
    #pragma unroll
    for (int f = 0; f < 8; ++f) {
        int q  = f * 256 + t;
        int i  = q >> 4;
        int c4 = (q & 15) * 4;
        const float4 xv = *(const float4*)(x + (size_t)i * NB + b0 + c4);
        const float xs[4] = {xv.x, xv.y, xv.z, xv.w};
        #pragma unroll
        for (int j = 0; j < 4; ++j) {
            float v = xs[j];
            float ea = __expf(-fabsf(v));
            float cdf = v > 0.f ? 1.f - 0.5f * ea : 0.5f * ea;
            int idx = (int)(cdf * 128.f);
            idx = idx > 127 ? 127 : idx;
            float d = (v - borders[idx]) * icl[idx];
            _Float16 hd = (_Float16)d;
            Lt[i][c4 + j] = ((uint32_t)idx << 4) |
                            ((uint32_t)__builtin_bit_cast(unsigned short, hd) << 16);
        }
    }
    __syncthreads();
    #pragma unroll
    for (int k = 0; k < 8; ++k) {
        int flat = t * 4 + k * 1024;            // word in 64b x 128i tile
        int bl = flat >> 7;
        int i0 = flat & 127;
        uint4 r = make_uint4(Lt[i0][bl], Lt[i0 + 1][bl],
                             Lt[i0 + 2][bl], Lt[i0 + 3][bl]);
        *(uint4*)(T2 + (size_t)(b0 + bl) * NI + i0) = r;
    }
}

// ---- K3: main. 1024 thr; 1024 b x 4 o x 128 i; async gll staging ---------
__global__ __launch_bounds__(1024, 4) void main_k(const uint32_t* __restrict__ Q2,
                                                  const uint32_t* __restrict__ T2,
                                                  float* __restrict__ out) {
    __shared__ __align__(16) uint32_t slab[2][PH * NG * 4];   // 2 x 32 KB
    const int t    = threadIdx.x;
    const int bx   = blockIdx.x;
    const int xcd  = bx & 7;                    // bx = xcd + 8*(s_hi + 4*bt)
    const int rest = bx >> 3;
    const int s    = xcd + ((rest & 3) << 3);   // o-slice (4 o); 4 slabs/XCD
    const int bt   = rest >> 2;                 // b-tile (1024 b)
    const int bme  = (bt << 10) | t;
    const uint32_t* Qs = Q2 + (size_t)s * (NI * NG * 4);
    const uint32_t* Tr = T2 + (size_t)bme * NI;

    float a0 = 0.f, a1 = 0.f, a2 = 0.f, a3 = 0.f;

    // prologue: async-stage phase 0 (32 KB, 2 x 16B per thread) + T words
    load_lds16(Qs + (size_t)t * 4,        &slab[0][t * 4]);
    load_lds16(Qs + (size_t)t * 4 + 4096, &slab[0][t * 4 + 4096]);
    uint4 tc0 = *(const uint4*)(Tr);
    uint4 tc1 = *(const uint4*)(Tr + 4);
    uint4 tc2 = *(const uint4*)(Tr + 8);
    uint4 tc3 = *(const uint4*)(Tr + 12);
    __syncthreads();                            // vmcnt(0) drain: slab0 ready

    #pragma unroll
    for (int p = 0; p < NPH; ++p) {
        const int cur = p & 1;
        uint4 tn0, tn1, tn2, tn3;
        if (p < NPH - 1) {                      // issue next stage FIRST
            const uint32_t* src = Qs + (size_t)(p + 1) * (PH * NG * 4) + t * 4;
            load_lds16(src,        &slab[cur ^ 1][t * 4]);
            load_lds16(src + 4096, &slab[cur ^ 1][t * 4 + 4096]);
            const uint32_t* tsrc = Tr + (p + 1) * PH;
            tn0 = *(const uint4*)(tsrc);
            tn1 = *(const uint4*)(tsrc + 4);
            tn2 = *(const uint4*)(tsrc + 8);
            tn3 = *(const uint4*)(tsrc + 12);
        }
        const char* sp = (const char*)&slab[cur][0];
        const uint32_t tw[PH] = {tc0.x, tc0.y, tc0.z, tc0.w,
                                 tc1.x, tc1.y, tc1.z, tc1.w,
                                 tc2.x, tc2.y, tc2.z, tc2.w,
                                 tc3.x, tc3.y, tc3.z, tc3.w};
        #pragma unroll
        for (int il = 0; il < PH; ++il) {
            uint32_t w   = tw[il];
            uint32_t off = w & 0xFFFFu;                     // idx*16 bytes
            uint32_t w2b = (w & 0xFFFF0000u) | 0x3C00u;     // {1.0h, d}
            uint4 q = *(const uint4*)(sp + il * 2048 + off);
            half2v w2 = __builtin_bit_cast(half2v, w2b);
            a0 = __builtin_amdgcn_fdot2(__builtin_bit_cast(half2v, q.x), w2, a0, false);
            a1 = __builtin_amdgcn_fdot2(__builtin_bit_cast(half2v, q.y), w2, a1, false);
            a2 = __builtin_amdgcn_fdot2(__builtin_bit_cast(half2v, q.z), w2, a2, false);
            a3 = __builtin_amdgcn_fdot2(__builtin_bit_cast(half2v, q.w), w2, a3, false);
        }
        if (p < NPH - 1) {
            tc0 = tn0; tc1 = tn1; tc2 = tn2; tc3 = tn3;
            __syncthreads();                    // drains stage(p+1)
        }
    }

    // epilogue: o = s*4 + {0..3}; 1024-lane contiguous runs per o
    size_t ob = (size_t)(s * 4) * NB + bme;
    __builtin_nontemporal_store(a0, out + ob);
    __builtin_nontemporal_store(a1, out + ob + NB);
    __builtin_nontemporal_store(a2, out + ob + 2 * (size_t)NB);
    __builtin_nontemporal_store(a3, out + ob + 3 * (size_t)NB);
}

extern "C" void kernel_launch(void* const* d_in, const int* in_sizes, int n_in,
                              void* d_out, int out_size, void* d_ws, size_t ws_size,
                              hipStream_t stream) {
    const float* x       = (const float*)d_in[0];
    const float* P       = (const float*)d_in[1];
    const float* borders = (const float*)d_in[2];
    const float* icl     = (const float*)d_in[3];
    float* out = (float*)d_out;

    uint32_t* Q2 = (uint32_t*)d_ws;                 // 8 MB
    uint32_t* T2 = Q2 + (size_t)NO * NI * NG;       // 4 MB

    hipLaunchKernelGGL(build_q, dim3(256), dim3(256), 0, stream, P, Q2);
    hipLaunchKernelGGL(build_t2, dim3(NB / 64), dim3(256), 0, stream,
                       x, borders, icl, T2);
    hipLaunchKernelGGL(main_k, dim3(256), dim3(1024), 0, stream, Q2, T2, out);
}